// Round 1
// baseline (318.086 us; speedup 1.0000x reference)
//
#include <hip/hip_runtime.h>
#include <hip/hip_bf16.h>
#include <math.h>

// Problem constants
#define TT 1024
#define HH 1024
#define NEXP 16
#define NI 704
#define SI 2048
#define KC 13312      // 16*704 + 2048 unified act width
#define RB 11264      // routed/shared boundary in stacked K
#define NKSPLIT 8
#define KSTEPS_PER 52 // 416 k-steps of 32 / 8 splits

typedef __attribute__((ext_vector_type(8))) __bf16 bf16x8;
typedef __attribute__((ext_vector_type(8))) short s16x8;
typedef __attribute__((ext_vector_type(4))) float f32x4;
typedef __attribute__((ext_vector_type(4))) unsigned int u32x4;

__device__ __forceinline__ unsigned short f2bf(float f) {
  unsigned u = __builtin_bit_cast(unsigned, f);
  u += 0x7fffu + ((u >> 16) & 1u);   // RNE
  return (unsigned short)(u >> 16);
}

// swizzled byte address in a [rows][32 bf16] LDS tile (pitch 64B).
// XOR of row bits into 16B-slot bits spreads the stride-64B fragment
// reads across banks (2-way residual = free per G4/m136).
__device__ __forceinline__ int swz(int row, int kg) {
  return ((row << 6) + (kg << 4)) ^ ((row & 7) << 4);
}

// ---------------- gating + h->bf16 ----------------
__global__ void k_gate(const float* __restrict__ h, const float* __restrict__ gw,
                       const float* __restrict__ bias, float* __restrict__ cw,
                       unsigned short* __restrict__ hb) {
  int t = blockIdx.x;
  int lane = threadIdx.x;
  const float* hr = h + (size_t)t * HH;
  for (int j = lane; j < HH; j += 64) hb[(size_t)t * HH + j] = f2bf(hr[j]);

  int e = lane >> 2, sub = lane & 3;
  const float* gr = gw + (size_t)e * HH;
  float acc = 0.f;
  for (int k = sub; k < HH; k += 4) acc += hr[k] * gr[k];
  acc += __shfl_down(acc, 1, 4);
  acc += __shfl_down(acc, 2, 4);
  __shared__ float lg[NEXP];
  if (sub == 0) lg[e] = acc;
  __syncthreads();
  if (lane == 0) {
    float sc[NEXP], s4[NEXP];
    for (int i = 0; i < NEXP; ++i) {
      sc[i] = 1.f / (1.f + expf(-lg[i]));
      s4[i] = sc[i] + bias[i];
    }
    // group score = sum of top-2 of 4
    float gs[4];
    for (int g = 0; g < 4; ++g) {
      float a = s4[4*g], b = s4[4*g+1], c = s4[4*g+2], d = s4[4*g+3];
      float mx01 = fmaxf(a, b), mn01 = fminf(a, b);
      float mx23 = fmaxf(c, d), mn23 = fminf(c, d);
      float top = fmaxf(mx01, mx23);
      float sec = (mx01 >= mx23) ? fmaxf(mn01, mx23) : fmaxf(mn23, mx01);
      gs[g] = top + sec;
    }
    int g1 = 0;
    for (int g = 1; g < 4; ++g) if (gs[g] > gs[g1]) g1 = g;   // ties -> lower idx
    int g2 = -1;
    for (int g = 0; g < 4; ++g) { if (g == g1) continue; if (g2 < 0 || gs[g] > gs[g2]) g2 = g; }
    float cwr[NEXP];
    bool used[NEXP];
    for (int i = 0; i < NEXP; ++i) { cwr[i] = 0.f; used[i] = false; }
    float wsum = 0.f;
    for (int it = 0; it < 6; ++it) {
      int best = -1; float bv = 0.f;
      for (int i = 0; i < NEXP; ++i) {
        int grp = i >> 2;
        if ((grp != g1 && grp != g2) || used[i]) continue;
        if (best < 0 || s4[i] > bv) { best = i; bv = s4[i]; }
      }
      used[best] = true;
      cwr[best] = sc[best];      // weights from UNBIASED scores
      wsum += sc[best];
    }
    float inv = 2.0f / wsum;     // ROUTED_SCALE folded in
    for (int i = 0; i < NEXP; ++i) cw[(size_t)t * NEXP + i] = cwr[i] * inv;
  }
}

// ---------------- up: cact[t, colbase+n] = silu(h@Wg)*(h@Wu) * scale ----------------
// block tile 128(M) x 64(N), both g and u; 4 waves (2x2), wave = 64x32 per matrix.
__global__ void k_up(const unsigned short* __restrict__ hb,
                     const float* __restrict__ Bg, const float* __restrict__ Bu,
                     int ldB, const float* __restrict__ cwbase,
                     unsigned short* __restrict__ cact, int is_shared) {
  __shared__ unsigned char lds[16384];  // A 8K | Bg 4K | Bu 4K
  int tid = threadIdx.x;
  int nt = blockIdx.x, mt = blockIdx.y, e = blockIdx.z;
  const float* BgE = Bg + (size_t)e * HH * ldB;
  const float* BuE = Bu + (size_t)e * HH * ldB;
  const float* cwp = is_shared ? nullptr : cwbase + e;
  int colbase = is_shared ? RB : e * NI;
  int t0 = mt * 128, n0 = nt * 64;
  int bn = tid & 63, bkg = tid >> 6;
  int wid = tid >> 6, lane = tid & 63;
  int wm = wid >> 1, wn = wid & 1;
  int lr = lane & 15, lg2 = lane >> 4;
  f32x4 accG[4][2] = {};
  f32x4 accU[4][2] = {};
  for (int k0 = 0; k0 < HH; k0 += 32) {
    __syncthreads();
    // stage A (bf16, 128x32), 2 x 16B chunks per thread
    #pragma unroll
    for (int cc = 0; cc < 2; ++cc) {
      int c = tid + cc * 256;
      int r = c >> 2, kg = c & 3;
      u32x4 v = *reinterpret_cast<const u32x4*>(hb + (size_t)(t0 + r) * HH + k0 + kg * 8);
      *reinterpret_cast<u32x4*>(&lds[swz(r, kg)]) = v;
    }
    // stage Bg/Bu: fp32 [32k x 64n] -> bf16 transposed [n][k] in LDS
    {
      s16x8 pg, pu;
      #pragma unroll
      for (int j = 0; j < 8; ++j) {
        int kk = k0 + bkg * 8 + j;
        pg[j] = (short)f2bf(BgE[(size_t)kk * ldB + n0 + bn]);
        pu[j] = (short)f2bf(BuE[(size_t)kk * ldB + n0 + bn]);
      }
      *reinterpret_cast<s16x8*>(&lds[8192  + swz(bn, bkg)]) = pg;
      *reinterpret_cast<s16x8*>(&lds[12288 + swz(bn, bkg)]) = pu;
    }
    __syncthreads();
    bf16x8 af[4], bg[2], bu[2];
    #pragma unroll
    for (int rf = 0; rf < 4; ++rf)
      af[rf] = __builtin_bit_cast(bf16x8,
          *reinterpret_cast<const s16x8*>(&lds[swz(wm*64 + rf*16 + lr, lg2)]));
    #pragma unroll
    for (int cf = 0; cf < 2; ++cf) {
      int n = wn * 32 + cf * 16 + lr;
      bg[cf] = __builtin_bit_cast(bf16x8, *reinterpret_cast<const s16x8*>(&lds[8192  + swz(n, lg2)]));
      bu[cf] = __builtin_bit_cast(bf16x8, *reinterpret_cast<const s16x8*>(&lds[12288 + swz(n, lg2)]));
    }
    #pragma unroll
    for (int rf = 0; rf < 4; ++rf)
      #pragma unroll
      for (int cf = 0; cf < 2; ++cf) {
        accG[rf][cf] = __builtin_amdgcn_mfma_f32_16x16x32_bf16(af[rf], bg[cf], accG[rf][cf], 0, 0, 0);
        accU[rf][cf] = __builtin_amdgcn_mfma_f32_16x16x32_bf16(af[rf], bu[cf], accU[rf][cf], 0, 0, 0);
      }
  }
  // epilogue: silu(g)*u * cw  -> bf16 cact
  #pragma unroll
  for (int rf = 0; rf < 4; ++rf)
    #pragma unroll
    for (int cf = 0; cf < 2; ++cf)
      #pragma unroll
      for (int r = 0; r < 4; ++r) {
        int row = wm * 64 + rf * 16 + lg2 * 4 + r;   // C row = (lane>>4)*4 + reg
        int col = wn * 32 + cf * 16 + lr;            // C col = lane&15
        int t = t0 + row;
        float g = accG[rf][cf][r], u = accU[rf][cf][r];
        float act = g / (1.f + __expf(-g)) * u;
        float scl = cwp ? cwp[(size_t)t * NEXP] : 1.0f;
        cact[(size_t)t * KC + colbase + n0 + col] = f2bf(act * scl);
      }
}

// ---------------- down: part[ks] = cact[:, kslice] @ Wstack[kslice, :] ----------------
__global__ void k_down(const unsigned short* __restrict__ cact,
                       const float* __restrict__ wd, const float* __restrict__ swd,
                       float* __restrict__ part) {
  __shared__ unsigned char lds[12288];  // A 8K | B 4K
  int tid = threadIdx.x;
  int nt = blockIdx.x, mt = blockIdx.y, ks = blockIdx.z;
  int t0 = mt * 128, n0 = nt * 64;
  int bn = tid & 63, bkg = tid >> 6;
  int wid = tid >> 6, lane = tid & 63;
  int wm = wid >> 1, wn = wid & 1;
  int lr = lane & 15, lg2 = lane >> 4;
  f32x4 acc[4][2] = {};
  for (int ksi = ks * KSTEPS_PER; ksi < (ks + 1) * KSTEPS_PER; ++ksi) {
    int k0 = ksi * 32;
    __syncthreads();
    #pragma unroll
    for (int cc = 0; cc < 2; ++cc) {
      int c = tid + cc * 256;
      int r = c >> 2, kg = c & 3;
      u32x4 v = *reinterpret_cast<const u32x4*>(cact + (size_t)(t0 + r) * KC + k0 + kg * 8);
      *reinterpret_cast<u32x4*>(&lds[swz(r, kg)]) = v;
    }
    {
      s16x8 pb;
      #pragma unroll
      for (int j = 0; j < 8; ++j) {
        int kk = k0 + bkg * 8 + j;   // wave-uniform (bkg const per wave)
        const float* src = (kk < RB) ? (wd + (size_t)kk * HH) : (swd + (size_t)(kk - RB) * HH);
        pb[j] = (short)f2bf(src[n0 + bn]);
      }
      *reinterpret_cast<s16x8*>(&lds[8192 + swz(bn, bkg)]) = pb;
    }
    __syncthreads();
    bf16x8 af[4], bfr[2];
    #pragma unroll
    for (int rf = 0; rf < 4; ++rf)
      af[rf] = __builtin_bit_cast(bf16x8,
          *reinterpret_cast<const s16x8*>(&lds[swz(wm*64 + rf*16 + lr, lg2)]));
    #pragma unroll
    for (int cf = 0; cf < 2; ++cf)
      bfr[cf] = __builtin_bit_cast(bf16x8,
          *reinterpret_cast<const s16x8*>(&lds[8192 + swz(wn*32 + cf*16 + lr, lg2)]));
    #pragma unroll
    for (int rf = 0; rf < 4; ++rf)
      #pragma unroll
      for (int cf = 0; cf < 2; ++cf)
        acc[rf][cf] = __builtin_amdgcn_mfma_f32_16x16x32_bf16(af[rf], bfr[cf], acc[rf][cf], 0, 0, 0);
  }
  float* p = part + (size_t)ks * TT * HH;
  #pragma unroll
  for (int rf = 0; rf < 4; ++rf)
    #pragma unroll
    for (int cf = 0; cf < 2; ++cf)
      #pragma unroll
      for (int r = 0; r < 4; ++r) {
        int row = wm * 64 + rf * 16 + lg2 * 4 + r;
        int col = wn * 32 + cf * 16 + lr;
        p[(size_t)(t0 + row) * HH + n0 + col] = acc[rf][cf][r];
      }
}

__global__ void k_reduce(const float* __restrict__ part, float* __restrict__ out) {
  int i = (blockIdx.x * blockDim.x + threadIdx.x) * 4;
  f32x4 s = {};
  #pragma unroll
  for (int sp = 0; sp < NKSPLIT; ++sp)
    s += *reinterpret_cast<const f32x4*>(part + (size_t)sp * TT * HH + i);
  *reinterpret_cast<f32x4*>(out + i) = s;
}

extern "C" void kernel_launch(void* const* d_in, const int* in_sizes, int n_in,
                              void* d_out, int out_size, void* d_ws, size_t ws_size,
                              hipStream_t stream) {
  const float* h    = (const float*)d_in[0];
  const float* gw   = (const float*)d_in[1];
  const float* bias = (const float*)d_in[2];
  const float* wg   = (const float*)d_in[3];
  const float* wu   = (const float*)d_in[4];
  const float* wd   = (const float*)d_in[5];
  const float* swg  = (const float*)d_in[6];
  const float* swu  = (const float*)d_in[7];
  const float* swd  = (const float*)d_in[8];
  float* out = (float*)d_out;

  char* ws = (char*)d_ws;
  // ws layout (~63 MB): hb 2MB | cw 64KB | cact 26MB | partials 32MB
  unsigned short* hb   = (unsigned short*)(ws);
  float*          cw   = (float*)(ws + 2097152);
  unsigned short* cact = (unsigned short*)(ws + 2162688);
  float*          part = (float*)(ws + 29425664);

  k_gate<<<TT, 64, 0, stream>>>(h, gw, bias, cw, hb);
  k_up<<<dim3(NI / 64, TT / 128, NEXP), 256, 0, stream>>>(hb, wg, wu, NI, cw, cact, 0);
  k_up<<<dim3(SI / 64, TT / 128, 1), 256, 0, stream>>>(hb, swg, swu, SI, nullptr, cact, 1);
  k_down<<<dim3(HH / 64, TT / 128, NKSPLIT), 256, 0, stream>>>(cact, wd, swd, part);
  k_reduce<<<1024, 256, 0, stream>>>(part, out);
}

// Round 2
// 259.278 us; speedup vs baseline: 1.2268x; 1.2268x over previous
//
#include <hip/hip_runtime.h>
#include <hip/hip_bf16.h>
#include <math.h>

// Problem constants
#define TT 1024
#define HH 1024
#define NEXP 16
#define NI 704
#define SI 2048
#define KC 13312      // 16*704 + 2048 unified act width
#define RB 11264      // routed/shared boundary in stacked K
#define NKS 4
#define KPER 3328     // 13312 / 4

typedef __attribute__((ext_vector_type(8))) __bf16 bf16x8;
typedef __attribute__((ext_vector_type(8))) short s16x8;
typedef __attribute__((ext_vector_type(4))) float f32x4;

__device__ __forceinline__ unsigned short f2bf(float f) {
  unsigned u = __builtin_bit_cast(unsigned, f);
  u += 0x7fffu + ((u >> 16) & 1u);   // RNE
  return (unsigned short)(u >> 16);
}

// Byte offset of 16B chunk (row, kg) in a [rows][32bf16] LDS tile with
// slot swizzle kg' = kg ^ ((row>>1)&3). 16 lanes reading rows r..r+15 at
// fixed kg spread over all 8 bank-quads exactly 2x (2-way = free, m136).
__device__ __forceinline__ int ldsOff(int row, int kg) {
  return (row * 4 + (kg ^ ((row >> 1) & 3))) * 16;
}

__device__ __forceinline__ void gl16(const void* g, void* l) {
  __builtin_amdgcn_global_load_lds((const __attribute__((address_space(1))) void*)g,
                                   (__attribute__((address_space(3))) void*)l, 16, 0, 0);
}

// ---------------- gating + h->bf16 ----------------
__global__ void k_gate(const float* __restrict__ h, const float* __restrict__ gw,
                       const float* __restrict__ bias, float* __restrict__ cw,
                       unsigned short* __restrict__ hb) {
  int t = blockIdx.x;
  int lane = threadIdx.x;
  const float* hr = h + (size_t)t * HH;
  for (int j = lane; j < HH; j += 64) hb[(size_t)t * HH + j] = f2bf(hr[j]);

  int e = lane >> 2, sub = lane & 3;
  const float* gr = gw + (size_t)e * HH;
  float acc = 0.f;
  for (int k = sub; k < HH; k += 4) acc += hr[k] * gr[k];
  acc += __shfl_down(acc, 1, 4);
  acc += __shfl_down(acc, 2, 4);
  __shared__ float lg[NEXP];
  if (sub == 0) lg[e] = acc;
  __syncthreads();
  if (lane == 0) {
    float sc[NEXP], s4[NEXP];
    for (int i = 0; i < NEXP; ++i) {
      sc[i] = 1.f / (1.f + expf(-lg[i]));
      s4[i] = sc[i] + bias[i];
    }
    float gs[4];
    for (int g = 0; g < 4; ++g) {
      float a = s4[4*g], b = s4[4*g+1], c = s4[4*g+2], d = s4[4*g+3];
      float mx01 = fmaxf(a, b), mn01 = fminf(a, b);
      float mx23 = fmaxf(c, d), mn23 = fminf(c, d);
      float top = fmaxf(mx01, mx23);
      float sec = (mx01 >= mx23) ? fmaxf(mn01, mx23) : fmaxf(mn23, mx01);
      gs[g] = top + sec;
    }
    int g1 = 0;
    for (int g = 1; g < 4; ++g) if (gs[g] > gs[g1]) g1 = g;
    int g2 = -1;
    for (int g = 0; g < 4; ++g) { if (g == g1) continue; if (g2 < 0 || gs[g] > gs[g2]) g2 = g; }
    float cwr[NEXP];
    bool used[NEXP];
    for (int i = 0; i < NEXP; ++i) { cwr[i] = 0.f; used[i] = false; }
    float wsum = 0.f;
    for (int it = 0; it < 6; ++it) {
      int best = -1; float bv = 0.f;
      for (int i = 0; i < NEXP; ++i) {
        int grp = i >> 2;
        if ((grp != g1 && grp != g2) || used[i]) continue;
        if (best < 0 || s4[i] > bv) { best = i; bv = s4[i]; }
      }
      used[best] = true;
      cwr[best] = sc[best];
      wsum += sc[best];
    }
    float inv = 2.0f / wsum;   // ROUTED_SCALE folded
    for (int i = 0; i < NEXP; ++i) cw[(size_t)t * NEXP + i] = cwr[i] * inv;
  }
}

// ---------------- transpose + fp32->bf16 convert ----------------
// in (matrix z): [R][C] fp32.  out[(z*C + c)*ldo + co + r] = bf16(in[z][r][c])
__global__ void k_tconv(const float* __restrict__ in, unsigned short* __restrict__ out,
                        int R, int C, int ldo, int co) {
  __shared__ float tile[64][65];
  const float* inz = in + (size_t)blockIdx.z * R * C;
  int r0 = blockIdx.y * 64, c0 = blockIdx.x * 64;
  int t = threadIdx.x;
  int rr = t >> 4, cc = (t & 15) * 4;
  #pragma unroll
  for (int i = 0; i < 4; ++i) {
    f32x4 v = *reinterpret_cast<const f32x4*>(inz + (size_t)(r0 + rr + i * 16) * C + c0 + cc);
    tile[rr + i*16][cc + 0] = v[0];
    tile[rr + i*16][cc + 1] = v[1];
    tile[rr + i*16][cc + 2] = v[2];
    tile[rr + i*16][cc + 3] = v[3];
  }
  __syncthreads();
  int c = t >> 2, rq = t & 3;
  s16x8 o0, o1;
  #pragma unroll
  for (int j = 0; j < 8; ++j) {
    o0[j] = (short)f2bf(tile[rq * 16 + j][c]);
    o1[j] = (short)f2bf(tile[rq * 16 + 8 + j][c]);
  }
  unsigned short* op = out + ((size_t)blockIdx.z * C + c0 + c) * ldo + co + r0 + rq * 16;
  *reinterpret_cast<s16x8*>(op) = o0;
  *reinterpret_cast<s16x8*>(op + 8) = o1;
}

// ---------------- up: cact = silu(h@Wg)*(h@Wu) * cw, dual-GEMM ----------------
// tile M=128 x N=64 (x2 matrices), 4 waves 2x2, B^T (N-major) bf16 weights,
// all staging via global_load_lds(16B), swizzled source + linear LDS.
__global__ __launch_bounds__(256) void k_up2(
    const unsigned short* __restrict__ hb,
    const unsigned short* __restrict__ Bg, const unsigned short* __restrict__ Bu,
    long long eStride, const float* __restrict__ cwbase,
    unsigned short* __restrict__ cact, int colbase_mult, int colbase_add) {
  __shared__ __align__(16) unsigned short lds[8192];  // A 8KB | Bg 4KB | Bu 4KB
  char* ldsb = (char*)lds;
  int tid = threadIdx.x;
  int nt = blockIdx.x, mt = blockIdx.y, e = blockIdx.z;
  const unsigned short* BgE = Bg + (size_t)e * eStride;
  const unsigned short* BuE = Bu + (size_t)e * eStride;
  int colbase = colbase_add + e * colbase_mult;
  int t0 = mt * 128, n0 = nt * 64;
  int w = tid >> 6, l = tid & 63;
  int wm = w >> 1, wn = w & 1;
  int lr = l & 15, lg2 = l >> 4;

  f32x4 accG[4][2] = {};
  f32x4 accU[4][2] = {};

  for (int k0 = 0; k0 < HH; k0 += 32) {
    // stage A (128x32): 512 chunks, 2 per thread
    #pragma unroll
    for (int c = 0; c < 2; ++c) {
      int ci = c * 256 + tid;
      int row = ci >> 2;
      int kg = (ci & 3) ^ ((row >> 1) & 3);
      gl16(hb + (size_t)(t0 + row) * HH + k0 + kg * 8,
           ldsb + (c * 256 + w * 64) * 16);
    }
    // stage Bg/Bu (64x32 each): 256 chunks each, 1 per thread
    {
      int row = tid >> 2;
      int kg = (tid & 3) ^ ((row >> 1) & 3);
      gl16(BgE + (size_t)(n0 + row) * HH + k0 + kg * 8, ldsb + 8192  + (w * 64) * 16);
      gl16(BuE + (size_t)(n0 + row) * HH + k0 + kg * 8, ldsb + 12288 + (w * 64) * 16);
    }
    __syncthreads();   // vmcnt(0) drain + barrier
    bf16x8 af[4], bg[2], bu[2];
    #pragma unroll
    for (int rf = 0; rf < 4; ++rf)
      af[rf] = *reinterpret_cast<const bf16x8*>(ldsb + ldsOff(wm * 64 + rf * 16 + lr, lg2));
    #pragma unroll
    for (int cf = 0; cf < 2; ++cf) {
      int n = wn * 32 + cf * 16 + lr;
      bg[cf] = *reinterpret_cast<const bf16x8*>(ldsb + 8192  + ldsOff(n, lg2));
      bu[cf] = *reinterpret_cast<const bf16x8*>(ldsb + 12288 + ldsOff(n, lg2));
    }
    #pragma unroll
    for (int rf = 0; rf < 4; ++rf)
      #pragma unroll
      for (int cf = 0; cf < 2; ++cf) {
        accG[rf][cf] = __builtin_amdgcn_mfma_f32_16x16x32_bf16(af[rf], bg[cf], accG[rf][cf], 0, 0, 0);
        accU[rf][cf] = __builtin_amdgcn_mfma_f32_16x16x32_bf16(af[rf], bu[cf], accU[rf][cf], 0, 0, 0);
      }
    __syncthreads();   // protect LDS before next stage
  }
  // epilogue: silu(g)*u * cw -> bf16 cact
  #pragma unroll
  for (int rf = 0; rf < 4; ++rf)
    #pragma unroll
    for (int cf = 0; cf < 2; ++cf)
      #pragma unroll
      for (int r = 0; r < 4; ++r) {
        int row = wm * 64 + rf * 16 + lg2 * 4 + r;
        int col = wn * 32 + cf * 16 + lr;
        int t = t0 + row;
        float g = accG[rf][cf][r], u = accU[rf][cf][r];
        float act = g / (1.f + __expf(-g)) * u;
        float scl = cwbase ? cwbase[(size_t)t * NEXP + e] : 1.0f;
        cact[(size_t)t * KC + colbase + n0 + col] = f2bf(act * scl);
      }
}

// ---------------- down: part[ks] = cact[:, kslice] @ WdT^T ----------------
// tile 128x128, 4 waves 2x2 (wave = 64x64), K split 4 ways.
__global__ __launch_bounds__(256) void k_down2(
    const unsigned short* __restrict__ cact,
    const unsigned short* __restrict__ wdb,   // [1024 n][13312 k] bf16
    float* __restrict__ part) {
  __shared__ __align__(16) unsigned short lds[8192];  // A 8KB | B 8KB
  char* ldsb = (char*)lds;
  int tid = threadIdx.x;
  int nt = blockIdx.x, mt = blockIdx.y, ks = blockIdx.z;
  int t0 = mt * 128, n0 = nt * 128;
  int w = tid >> 6, l = tid & 63;
  int wm = w >> 1, wn = w & 1;
  int lr = l & 15, lg2 = l >> 4;
  f32x4 acc[4][4] = {};
  int kbase = ks * KPER;
  for (int kk = 0; kk < KPER; kk += 32) {
    int k0 = kbase + kk;
    #pragma unroll
    for (int c = 0; c < 2; ++c) {
      int ci = c * 256 + tid;
      int row = ci >> 2;
      int kg = (ci & 3) ^ ((row >> 1) & 3);
      gl16(cact + (size_t)(t0 + row) * KC + k0 + kg * 8,
           ldsb + (c * 256 + w * 64) * 16);
      gl16(wdb + (size_t)(n0 + row) * KC + k0 + kg * 8,
           ldsb + 8192 + (c * 256 + w * 64) * 16);
    }
    __syncthreads();
    bf16x8 af[4], bb[4];
    #pragma unroll
    for (int rf = 0; rf < 4; ++rf)
      af[rf] = *reinterpret_cast<const bf16x8*>(ldsb + ldsOff(wm * 64 + rf * 16 + lr, lg2));
    #pragma unroll
    for (int cf = 0; cf < 4; ++cf)
      bb[cf] = *reinterpret_cast<const bf16x8*>(ldsb + 8192 + ldsOff(wn * 64 + cf * 16 + lr, lg2));
    #pragma unroll
    for (int rf = 0; rf < 4; ++rf)
      #pragma unroll
      for (int cf = 0; cf < 4; ++cf)
        acc[rf][cf] = __builtin_amdgcn_mfma_f32_16x16x32_bf16(af[rf], bb[cf], acc[rf][cf], 0, 0, 0);
    __syncthreads();
  }
  float* p = part + (size_t)ks * TT * HH;
  #pragma unroll
  for (int rf = 0; rf < 4; ++rf)
    #pragma unroll
    for (int cf = 0; cf < 4; ++cf)
      #pragma unroll
      for (int r = 0; r < 4; ++r) {
        int row = wm * 64 + rf * 16 + lg2 * 4 + r;
        int col = wn * 64 + cf * 16 + lr;
        p[(size_t)(t0 + row) * HH + n0 + col] = acc[rf][cf][r];
      }
}

__global__ void k_reduce(const float* __restrict__ part, float* __restrict__ out) {
  int i = (blockIdx.x * blockDim.x + threadIdx.x) * 4;
  f32x4 s = {};
  #pragma unroll
  for (int sp = 0; sp < NKS; ++sp)
    s += *reinterpret_cast<const f32x4*>(part + (size_t)sp * TT * HH + i);
  *reinterpret_cast<f32x4*>(out + i) = s;
}

extern "C" void kernel_launch(void* const* d_in, const int* in_sizes, int n_in,
                              void* d_out, int out_size, void* d_ws, size_t ws_size,
                              hipStream_t stream) {
  const float* h    = (const float*)d_in[0];
  const float* gw   = (const float*)d_in[1];
  const float* bias = (const float*)d_in[2];
  const float* wg   = (const float*)d_in[3];
  const float* wu   = (const float*)d_in[4];
  const float* wd   = (const float*)d_in[5];
  const float* swg  = (const float*)d_in[6];
  const float* swu  = (const float*)d_in[7];
  const float* swd  = (const float*)d_in[8];
  float* out = (float*)d_out;

  char* ws = (char*)d_ws;
  // Layout (peak 84 MB). wdb/part alias the up-weight region: wd/swd are
  // converted only AFTER both k_up2 launches complete (stream-ordered).
  unsigned short* hb   = (unsigned short*)(ws);                 // 2 MB
  float*          cw   = (float*)(ws + 2097152);                // 64 KB
  unsigned short* wgb  = (unsigned short*)(ws + 2162688);       // 23.07 MB [16][704][1024]
  unsigned short* wub  = (unsigned short*)(ws + 25231360);      // 23.07 MB
  unsigned short* swgb = (unsigned short*)(ws + 48300032);      // 4 MB [2048][1024]
  unsigned short* swub = (unsigned short*)(ws + 52494336);      // 4 MB
  unsigned short* cact = (unsigned short*)(ws + 56688640);      // 27.26 MB [1024][13312]
  unsigned short* wdb  = (unsigned short*)(ws + 2162688);       // alias wgb: 27.26 MB [1024][13312]
  float*          part = (float*)(ws + 29425664);               // alias wub: 16 MB

  // weight converts (transpose to N-major bf16)
  k_tconv<<<dim3(11, 16, 16), 256, 0, stream>>>(wg,  wgb,  HH, NI, HH, 0);
  k_tconv<<<dim3(11, 16, 16), 256, 0, stream>>>(wu,  wub,  HH, NI, HH, 0);
  k_tconv<<<dim3(32, 16, 1),  256, 0, stream>>>(swg, swgb, HH, SI, HH, 0);
  k_tconv<<<dim3(32, 16, 1),  256, 0, stream>>>(swu, swub, HH, SI, HH, 0);

  k_gate<<<TT, 64, 0, stream>>>(h, gw, bias, cw, hb);

  k_up2<<<dim3(NI / 64, TT / 128, NEXP), 256, 0, stream>>>(
      hb, wgb, wub, (long long)NI * HH, cw, cact, NI, 0);
  k_up2<<<dim3(SI / 64, TT / 128, 1), 256, 0, stream>>>(
      hb, swgb, swub, 0LL, nullptr, cact, 0, RB);

  // down-weight converts into the (now dead) up-weight region
  k_tconv<<<dim3(16, 176, 1), 256, 0, stream>>>(wd,  wdb, RB, HH, KC, 0);
  k_tconv<<<dim3(16, 32, 1),  256, 0, stream>>>(swd, wdb, SI, HH, KC, RB);

  k_down2<<<dim3(HH / 128, TT / 128, NKS), 256, 0, stream>>>(cact, wdb, part);
  k_reduce<<<1024, 256, 0, stream>>>(part, out);
}